// Round 6
// baseline (20.259 us; speedup 1.0000x reference)
//
#include <hip/hip_runtime.h>

namespace {

constexpr int T = 48;
constexpr int MAXTRI = 4;
constexpr float EPSF = 1e-8f;
constexpr int NWAVE = 8;
constexpr int NBLK = 512;    // 8x8x8 blocks of 4x4x4 cells
constexpr int NLOC = 125;    // 5x5x5 halo region per block
constexpr int NHALO = 61;    // NLOC - 64 owned

// ---------------- compile-time reproduction of np.random.RandomState(0) ----
struct Tables {
  int tri[T][MAXTRI][3];
  int ntri[T];
};

struct MT {
  unsigned mt[624];
  int pos;
  constexpr MT() : mt{}, pos(624) {
    unsigned s = 0u;  // RandomState(0): scalar seed -> init_genrand(0)
    for (int i = 0; i < 624; ++i) {
      mt[i] = s;
      s = 1812433253u * (s ^ (s >> 30)) + (unsigned)(i + 1);
    }
  }
  constexpr unsigned next() {
    if (pos == 624) {
      for (int i = 0; i < 624; ++i) {
        unsigned y = (mt[i] & 0x80000000u) | (mt[(i + 1) % 624] & 0x7fffffffu);
        unsigned v = mt[(i + 397) % 624] ^ (y >> 1);
        if (y & 1u) v ^= 0x9908b0dfu;
        mt[i] = v;
      }
      pos = 0;
    }
    unsigned y = mt[pos++];
    y ^= y >> 11;
    y ^= (y << 7) & 0x9d2c5680u;
    y ^= (y << 15) & 0xefc60000u;
    y ^= y >> 18;
    return y;
  }
  constexpr unsigned draw(unsigned mask, unsigned rng) {
    unsigned v = next() & mask;
    while (v > rng) v = next() & mask;
    return v;
  }
};

constexpr Tables make_tables() {
  Tables tb{};
  MT g{};
  for (int t = 0; t < T; ++t)
    for (int p = 0; p < MAXTRI; ++p)
      for (int c = 0; c < 3; ++c)
        tb.tri[t][p][c] = (int)g.draw(15u, 11u);
  for (int t = 0; t < T; ++t)
    tb.ntri[t] = 1 + (int)g.draw(3u, 3u);
  return tb;
}

constexpr Tables TB = make_tables();

// compile-time balanced t-partition across 8 waves, weight = 3*ntri+2
struct Splits { int s[NWAVE + 1]; };
constexpr Splits make_splits() {
  Splits sp{};
  int total = 0;
  for (int t = 0; t < T; ++t) total += 3 * TB.ntri[t] + 2;
  sp.s[0] = 0;
  int acc = 0, t = 0;
  for (int w = 1; w < NWAVE; ++w) {
    const int target = (total * w + NWAVE / 2) / NWAVE;
    while (t < T && acc < target) { acc += 3 * TB.ntri[t] + 2; ++t; }
    sp.s[w] = t;
  }
  sp.s[NWAVE] = T;
  return sp;
}
constexpr Splits SP = make_splits();

// local-cell maps: flat (li*25+lj*5+lk) -> cell index (owned-first), and
// halo ordinal -> flat coords
struct Lmap {
  int lidx[NLOC];
  int halo[NHALO];
};
constexpr Lmap make_lmap() {
  Lmap m{};
  int h = 64;
  for (int li = 0; li < 5; ++li)
    for (int lj = 0; lj < 5; ++lj)
      for (int lk = 0; lk < 5; ++lk) {
        int f = li * 25 + lj * 5 + lk;
        if (li < 4 && lj < 4 && lk < 4) m.lidx[f] = li * 16 + lj * 4 + lk;
        else { m.lidx[f] = h; m.halo[h - 64] = f; ++h; }
      }
  return m;
}
constexpr Lmap LM = make_lmap();

// EDGES: (dx,dy,dz,axis)
constexpr int EDX[12] = {0,1,0,0,0,1,0,0,0,1,1,0};
constexpr int EDY[12] = {0,0,1,0,0,0,1,0,0,0,1,1};
constexpr int EDZ[12] = {0,0,0,0,1,1,1,1,0,0,0,0};
constexpr int EAX[12] = {0,1,0,1,0,1,0,1,2,2,2,2};

// ---------------- fully-unrolled per-t accumulation -------------------------
template <int t, int p>
__device__ __forceinline__ void tri_normals(const float (&vx)[12], const float (&vy)[12],
                                            const float (&vz)[12], float (&nx)[MAXTRI],
                                            float (&ny)[MAXTRI], float (&nz)[MAXTRI]) {
  if constexpr (p < TB.ntri[t]) {
    constexpr int e0 = TB.tri[t][p][0];
    constexpr int e1 = TB.tri[t][p][1];
    constexpr int e2 = TB.tri[t][p][2];
    float ax = vx[e1] - vx[e0], ay = vy[e1] - vy[e0], az = vz[e1] - vz[e0];
    float bx = vx[e2] - vx[e0], by = vy[e2] - vy[e0], bz = vz[e2] - vz[e0];
    float cx = ay * bz - az * by;
    float cy = az * bx - ax * bz;
    float cz = ax * by - ay * bx;
    float nrm = __builtin_amdgcn_sqrtf(cx * cx + cy * cy + cz * cz);
    float inv = __builtin_amdgcn_rcpf(nrm + EPSF);
    nx[p] = cx * inv; ny[p] = cy * inv; nz[p] = cz * inv;
    tri_normals<t, p + 1>(vx, vy, vz, nx, ny, nz);
  }
}

template <int t>
__device__ __forceinline__ void accum_t(const float (&vx)[12], const float (&vy)[12],
                                        const float (&vz)[12], float tv, float& lw, float& ex,
                                        float& ey, float& ez, float& ss, float& pp) {
  constexpr int nt = TB.ntri[t];
  float nx[MAXTRI] = {0.f, 0.f, 0.f, 0.f};
  float ny[MAXTRI] = {0.f, 0.f, 0.f, 0.f};
  float nz[MAXTRI] = {0.f, 0.f, 0.f, 0.f};
  tri_normals<t, 0>(vx, vy, vz, nx, ny, nz);

  float within = 0.f;
  if constexpr (nt > 1) {
    float dx = nx[1] - nx[0], dy = ny[1] - ny[0], dz = nz[1] - nz[0];
    within += dx * dx + dy * dy + dz * dz;
  }
  if constexpr (nt > 2) {
    float dx = nx[2] - nx[1], dy = ny[2] - ny[1], dz = nz[2] - nz[1];
    within += dx * dx + dy * dy + dz * dz;
  }
  if constexpr (nt > 3) {
    float dx = nx[3] - nx[2], dy = ny[3] - ny[2], dz = nz[3] - nz[2];
    within += dx * dx + dy * dy + dz * dz;
  }

  float mx = nx[0], my = ny[0], mz = nz[0];
  if constexpr (nt > 1) { mx += nx[1]; my += ny[1]; mz += nz[1]; }
  if constexpr (nt > 2) { mx += nx[2]; my += ny[2]; mz += nz[2]; }
  if constexpr (nt > 3) { mx += nx[3]; my += ny[3]; mz += nz[3]; }
  constexpr float invn = 1.0f / (float)nt;
  mx *= invn; my *= invn; mz *= invn;

  lw += tv * within;
  ex += tv * mx; ey += tv * my; ez += tv * mz;
  ss += tv * (mx * mx + my * my + mz * mz);
  pp += tv;
}

template <int t0, int t1>
__device__ __forceinline__ void accum_range(const float (&vx)[12], const float (&vy)[12],
                                            const float (&vz)[12], const float* s_topo, int cellc,
                                            float& lw, float& ex, float& ey, float& ez, float& ss,
                                            float& pp) {
  if constexpr (t0 < t1) {
    float tv = s_topo[t0 * NLOC + cellc];
    accum_t<t0>(vx, vy, vz, tv, lw, ex, ey, ez, ss, pp);
    accum_range<t0 + 1, t1>(vx, vy, vz, s_topo, cellc, lw, ex, ey, ez, ss, pp);
  }
}

__device__ __forceinline__ void accum_dispatch(int wid, const float (&vx)[12],
                                               const float (&vy)[12], const float (&vz)[12],
                                               const float* s_topo, int cellc, float& lw,
                                               float& ex, float& ey, float& ez, float& ss,
                                               float& pp) {
  switch (wid) {
    case 0:  accum_range<SP.s[0], SP.s[1]>(vx, vy, vz, s_topo, cellc, lw, ex, ey, ez, ss, pp); break;
    case 1:  accum_range<SP.s[1], SP.s[2]>(vx, vy, vz, s_topo, cellc, lw, ex, ey, ez, ss, pp); break;
    case 2:  accum_range<SP.s[2], SP.s[3]>(vx, vy, vz, s_topo, cellc, lw, ex, ey, ez, ss, pp); break;
    case 3:  accum_range<SP.s[3], SP.s[4]>(vx, vy, vz, s_topo, cellc, lw, ex, ey, ez, ss, pp); break;
    case 4:  accum_range<SP.s[4], SP.s[5]>(vx, vy, vz, s_topo, cellc, lw, ex, ey, ez, ss, pp); break;
    case 5:  accum_range<SP.s[5], SP.s[6]>(vx, vy, vz, s_topo, cellc, lw, ex, ey, ez, ss, pp); break;
    case 6:  accum_range<SP.s[6], SP.s[7]>(vx, vy, vz, s_topo, cellc, lw, ex, ey, ez, ss, pp); break;
    default: accum_range<SP.s[7], SP.s[8]>(vx, vy, vz, s_topo, cellc, lw, ex, ey, ez, ss, pp); break;
  }
}

__device__ __forceinline__ void build_verts(const float* __restrict__ offset, int ci, int cj,
                                            int ck, float (&vx)[12], float (&vy)[12],
                                            float (&vz)[12]) {
#pragma unroll
  for (int e = 0; e < 12; ++e) {
    const int gi = ci + EDX[e], gj = cj + EDY[e], gk = ck + EDZ[e];
    const int a = EAX[e];
    const float disp = offset[a * 35937 + gi * 1089 + gj * 33 + gk];
    float px = (float)gi, py = (float)gj, pz = (float)gk;
    const float d = 0.5f + disp;
    if (a == 0) px += d; else if (a == 1) py += d; else pz += d;
    vx[e] = px; vy[e] = py; vz[e] = pz;
  }
}

// ---------------- halo kernel: fully block-local ----------------------------
// 512 blocks x 512 threads. Block owns a 4x4x4 cell volume, computes e/s/P
// for the 5x5x5 halo region in LDS (owner-computes-left cross pairs), and
// writes ONE partial float. No atomics, no grid sync, no global intermediates.
__global__ __launch_bounds__(512, 4) void halo_kernel(const float* __restrict__ offset,
                                                      const float* __restrict__ topo,
                                                      float* __restrict__ ws_part) {
  __shared__ float s_topo[T * NLOC];      // 24.0 KB  [t][cell]
  __shared__ float s_part[6][NWAVE][64];  // 12.3 KB
  __shared__ float s_esp[5][128];         //  2.5 KB  e/s/P per local cell
  __shared__ float s_lw;
  const int tid = threadIdx.x, lane = tid & 63, wid = tid >> 6;
  const int bi = blockIdx.x >> 6, bj = (blockIdx.x >> 3) & 7, bk = blockIdx.x & 7;
  const int ci0 = bi * 4, cj0 = bj * 4, ck0 = bk * 4;

  // ---- stage topology for the 125 local cells (clamped rows for OOB halo) --
  {
    const float4* g4 = reinterpret_cast<const float4*>(topo);
#pragma unroll
    for (int it = 0; it < 3; ++it) {
      int u = tid + it * 512;
      if (u < NLOC * 12) {
        int c = u / 12, q = u % 12;  // 12 float4 per topology row
        int li, lj, lk;
        if (c < 64) { li = c >> 4; lj = (c >> 2) & 3; lk = c & 3; }
        else { int f = LM.halo[c - 64]; li = f / 25; lj = (f / 5) % 5; lk = f % 5; }
        int ci = min(ci0 + li, 31), cj = min(cj0 + lj, 31), ck = min(ck0 + lk, 31);
        int g = (ci << 10) + (cj << 5) + ck;
        float4 v = g4[g * 12 + q];
        int tq = q * 4;
        s_topo[(tq + 0) * NLOC + c] = v.x;
        s_topo[(tq + 1) * NLOC + c] = v.y;
        s_topo[(tq + 2) * NLOC + c] = v.z;
        s_topo[(tq + 3) * NLOC + c] = v.w;
      }
    }
  }
  __syncthreads();

  // ---- pass 0: owned cells 0..63 (lane = cell) -----------------------------
  {
    const int li = lane >> 4, lj = (lane >> 2) & 3, lk = lane & 3;
    float vx[12], vy[12], vz[12];
    build_verts(offset, ci0 + li, cj0 + lj, ck0 + lk, vx, vy, vz);
    float lw = 0.f, ex = 0.f, ey = 0.f, ez = 0.f, ss = 0.f, pp = 0.f;
    accum_dispatch(wid, vx, vy, vz, s_topo, lane, lw, ex, ey, ez, ss, pp);
    s_part[0][wid][lane] = ex;
    s_part[1][wid][lane] = ey;
    s_part[2][wid][lane] = ez;
    s_part[3][wid][lane] = ss;
    s_part[4][wid][lane] = pp;
    s_part[5][wid][lane] = lw;
  }
  __syncthreads();

  if (tid < 384) {
    const int q = tid >> 6, c = tid & 63;
    float v = 0.f;
#pragma unroll
    for (int w = 0; w < NWAVE; ++w) v += s_part[q][w][c];
    if (q < 5) s_esp[q][c] = v;
    else {
#pragma unroll
      for (int off = 32; off > 0; off >>= 1) v += __shfl_down(v, off);
      if (c == 0) s_lw = v;
    }
  }
  __syncthreads();

  // ---- pass 1: halo cells 64..124 (lane = halo ordinal) --------------------
  if (lane < NHALO) {
    const int f = LM.halo[lane];
    const int li = f / 25, lj = (f / 5) % 5, lk = f % 5;
    const int ci = min(ci0 + li, 31), cj = min(cj0 + lj, 31), ck = min(ck0 + lk, 31);
    float vx[12], vy[12], vz[12];
    build_verts(offset, ci, cj, ck, vx, vy, vz);
    float lw = 0.f, ex = 0.f, ey = 0.f, ez = 0.f, ss = 0.f, pp = 0.f;
    accum_dispatch(wid, vx, vy, vz, s_topo, 64 + lane, lw, ex, ey, ez, ss, pp);
    s_part[0][wid][lane] = ex;
    s_part[1][wid][lane] = ey;
    s_part[2][wid][lane] = ez;
    s_part[3][wid][lane] = ss;
    s_part[4][wid][lane] = pp;
  }
  __syncthreads();

  if (tid < 320) {
    const int q = tid >> 6, c = tid & 63;
    if (c < NHALO) {
      float v = 0.f;
#pragma unroll
      for (int w = 0; w < NWAVE; ++w) v += s_part[q][w][c];
      s_esp[q][64 + c] = v;
    }
  }
  __syncthreads();

  // ---- cross terms, owner-computes-left, all from LDS ----------------------
  if (tid < 64) {
    const int li = tid >> 4, lj = (tid >> 2) & 3, lk = tid & 3;
    const int f = li * 25 + lj * 5 + lk;
    const int gi = ci0 + li, gj = cj0 + lj, gk = ck0 + lk;
    const float exl = s_esp[0][tid], eyl = s_esp[1][tid], ezl = s_esp[2][tid];
    const float sl = s_esp[3][tid], pl = s_esp[4][tid];
    float acc = 0.f;
    if (gi < 31) {
      int r = LM.lidx[f + 25];
      acc += sl * s_esp[4][r] + s_esp[3][r] * pl -
             2.f * (exl * s_esp[0][r] + eyl * s_esp[1][r] + ezl * s_esp[2][r]);
    }
    if (gj < 31) {
      int r = LM.lidx[f + 5];
      acc += sl * s_esp[4][r] + s_esp[3][r] * pl -
             2.f * (exl * s_esp[0][r] + eyl * s_esp[1][r] + ezl * s_esp[2][r]);
    }
    if (gk < 31) {
      int r = LM.lidx[f + 1];
      acc += sl * s_esp[4][r] + s_esp[3][r] * pl -
             2.f * (exl * s_esp[0][r] + eyl * s_esp[1][r] + ezl * s_esp[2][r]);
    }
#pragma unroll
    for (int off = 32; off > 0; off >>= 1) acc += __shfl_down(acc, off);
    if (tid == 0) ws_part[blockIdx.x] = acc + s_lw;
  }
}

// ---------------- finisher: sum 512 partials --------------------------------
__global__ __launch_bounds__(512) void finish_kernel(const float* __restrict__ ws_part,
                                                     float* __restrict__ out) {
  const int tid = threadIdx.x;
  float v = ws_part[tid];
#pragma unroll
  for (int off = 32; off > 0; off >>= 1) v += __shfl_down(v, off);
  __shared__ float w[8];
  if ((tid & 63) == 0) w[tid >> 6] = v;
  __syncthreads();
  if (tid == 0) {
    float s = 0.f;
#pragma unroll
    for (int i = 0; i < 8; ++i) s += w[i];
    out[0] = s;
  }
}

}  // namespace

extern "C" void kernel_launch(void* const* d_in, const int* in_sizes, int n_in,
                              void* d_out, int out_size, void* d_ws, size_t ws_size,
                              hipStream_t stream) {
  const float* offset = (const float*)d_in[0];   // [3][33][33][33] f32
  const float* topo = (const float*)d_in[1];     // [32768][48] f32
  float* out = (float*)d_out;                    // [1] f32
  float* ws_part = (float*)d_ws;                 // 512 floats

  hipLaunchKernelGGL(halo_kernel, dim3(NBLK), dim3(512), 0, stream,
                     offset, topo, ws_part);
  hipLaunchKernelGGL(finish_kernel, dim3(1), dim3(512), 0, stream, ws_part, out);
}